// Round 3
// baseline (18160.170 us; speedup 1.0000x reference)
//
#include <hip/hip_runtime.h>

// ---------------------------------------------------------------------------
// Persistent-kernel Seq2Seq LSTM. One kernel runs all 256 encoder steps +
// 24 decoder steps; 256 WGs (1/CU) synchronize via per-m-tile device-scope
// flags. Each WG owns M-tile 64 x N-tile 128 (gates) for the whole sequence
// -> weight slab stays L2-resident. f16 MFMA 16x16x32, fp32 cell state.
// R3 fix: no skipped LDS stage (uninit LDS * 0 = NaN). K0 padded to 64 only:
// K=576 -> 9 chunks, every chunk stages real data.
// ---------------------------------------------------------------------------

typedef _Float16 half_t;
typedef _Float16 half8 __attribute__((ext_vector_type(8)));
typedef float floatx4 __attribute__((ext_vector_type(4)));

#define B_ 1024
#define S_ 256
#define IN_ 64
#define H_ 512
#define NT_ 8
#define HOR_ 24
#define NG_ 2048       // 4*H
#define BH_ (B_ * H_)

__device__ __forceinline__ void async_cp16(const void* g, void* l) {
  __builtin_amdgcn_global_load_lds((const __attribute__((address_space(1))) void*)g,
                                   (__attribute__((address_space(3))) void*)l,
                                   16, 0, 0);
}

__device__ __forceinline__ float fast_sig(float x) {
  return __builtin_amdgcn_rcpf(1.0f + __builtin_amdgcn_exp2f(-1.44269504f * x));
}
__device__ __forceinline__ float fast_tanh(float x) {
  float xx = fminf(10.0f, fmaxf(-10.0f, x));
  float e = __builtin_amdgcn_exp2f(2.88539008f * xx);
  return (e - 1.0f) * __builtin_amdgcn_rcpf(e + 1.0f);
}

__device__ __forceinline__ void wait_ge(int* f, int tgt) {
  while (__hip_atomic_load(f, __ATOMIC_ACQUIRE, __HIP_MEMORY_SCOPE_AGENT) < tgt)
    __builtin_amdgcn_s_sleep(1);
}
__device__ __forceinline__ void bump(int* f) {
  __hip_atomic_fetch_add(f, 1, __ATOMIC_RELEASE, __HIP_MEMORY_SCOPE_AGENT);
}

// ---------------- setup kernels ----------------

__global__ void k_xT(const float* __restrict__ x, half_t* __restrict__ xf) {
  int i = blockIdx.x * 256 + threadIdx.x;  // (t*B + b)*64 + e
  int e = i & 63;
  int tb = i >> 6;
  int t = tb >> 10;         // B_ = 1024
  int b = tb & 1023;
  xf[i] = (half_t)x[((size_t)b * S_ + t) * 64 + e];
}

// Pack [Wih(pad)|Whh] -> Wp (2048 x K) f16, packed row r = 4*j+g <- src g*512+j.
__global__ void k_pack(const float* __restrict__ Wih, const float* __restrict__ Whh,
                       const float* __restrict__ bias,
                       half_t* __restrict__ Wp, float* __restrict__ bp,
                       int K0real, int K0pad, int K) {
  int i = blockIdx.x * 256 + threadIdx.x;
  if (i >= NG_ * K) return;
  int r = i / K;
  int k = i - r * K;
  int j = r >> 2, g = r & 3;
  int src = g * H_ + j;
  float v;
  if (k < K0pad) v = (k < K0real) ? Wih[src * K0real + k] : 0.0f;
  else           v = Whh[src * H_ + (k - K0pad)];
  Wp[i] = (half_t)v;
  if (k == 0) bp[r] = bias[src];
}

__global__ void k_init(float* c0, float* c1, half_t* h0, half_t* h1, half_t* dpad,
                       int* fh0, int* fh1, int* ffc) {
  int i = blockIdx.x * 256 + threadIdx.x;  // grid covers B*H
  if (i < BH_) {
    c0[i] = 0.0f; c1[i] = 0.0f;
    h0[i] = (half_t)0.0f; h0[i + BH_] = (half_t)0.0f; h0[i + 2 * BH_] = (half_t)0.0f;
    h1[i] = (half_t)0.0f; h1[i + BH_] = (half_t)0.0f; h1[i + 2 * BH_] = (half_t)0.0f;
  }
  if (i < B_ * 64) dpad[i] = (half_t)0.0f;
  if (i < 384 * 16) { int v = (i < 32) ? 16 : 0; fh0[i] = v; fh1[i] = v; }
  if (i < 32 * 16) ffc[i] = 0;
}

// ---------------- fused GEMM + LSTM-cell (device) ----------------
// WG tile 64(M) x 128(N gates), 4 waves (2M x 2N), wave tile 32x64.
// BK=64 chunks, double-buffered LDS, global_load_lds width=16,
// XOR-by-row swizzle (2-way = free).
// mode0: chunk0 = s0 (row stride str0, 64 k), chunks 1..NC-1 = sA + (c-1)*64.
// else:  c<8 -> sA + c*64, c>=8 -> sB + (c-8)*64.

__device__ __forceinline__ void gemm_cell(
    half_t* ldsA, half_t* ldsB, bool mode0,
    const half_t* s0, int str0, const half_t* sA, const half_t* sB,
    const half_t* __restrict__ Bs, int K, int NC,
    const float* __restrict__ bp, float* __restrict__ cio,
    half_t* __restrict__ hout, int M0, int N0) {
  const int tid = threadIdx.x;
  const int l = tid & 63, w = tid >> 6;
  const int wm = w >> 1, wn = w & 1;
  const int fr = l & 15, q = l >> 4;
  const int r8 = l >> 3, c8 = l & 7;

  floatx4 acc[2][4];
#pragma unroll
  for (int a = 0; a < 2; ++a)
#pragma unroll
    for (int b = 0; b < 4; ++b) acc[a][b] = (floatx4){0.f, 0.f, 0.f, 0.f};

  auto stage = [&](int c, int buf) {
    const half_t* as;
    int str;
    if (mode0) {
      as = (c == 0) ? s0 : sA + (size_t)(c - 1) * 64;
      str = (c == 0) ? str0 : H_;
    } else {
      as = (c < 8) ? sA + (size_t)c * 64 : sB + (size_t)(c - 8) * 64;
      str = H_;
    }
    half_t* la = ldsA + buf * 4096;
    half_t* lb = ldsB + buf * 8192;
#pragma unroll
    for (int ii = 0; ii < 2; ++ii) {
      int i = 2 * w + ii;
      int r = 8 * i + r8;
      int sc = c8 ^ (r & 7);
      async_cp16(as + (size_t)r * str + sc * 8, la + i * 512);
    }
    const half_t* bsrc = Bs + (size_t)c * 64;
#pragma unroll
    for (int jj = 0; jj < 4; ++jj) {
      int j = 4 * w + jj;
      int r = 8 * j + r8;
      int sc = c8 ^ (r & 7);
      async_cp16(bsrc + (size_t)r * K + sc * 8, lb + j * 512);
    }
  };

  stage(0, 0);
  int buf = 0;
  for (int c = 0; c < NC; ++c) {
    __syncthreads();                        // staged buf ready; prior compute done
    if (c + 1 < NC) stage(c + 1, buf ^ 1);  // prefetch overlaps compute below
    const half_t* la = ldsA + buf * 4096;
    const half_t* lb = ldsB + buf * 8192;
#pragma unroll
    for (int kk = 0; kk < 2; ++kk) {
      half8 av[2], bv[4];
#pragma unroll
      for (int mt = 0; mt < 2; ++mt) {
        int r = wm * 32 + mt * 16 + fr;
        int sc = (4 * kk + q) ^ (fr & 7);
        av[mt] = *(const half8*)(la + r * 64 + sc * 8);
      }
#pragma unroll
      for (int nt = 0; nt < 4; ++nt) {
        int r = wn * 64 + nt * 16 + fr;
        int sc = (4 * kk + q) ^ (fr & 7);
        bv[nt] = *(const half8*)(lb + r * 64 + sc * 8);
      }
#pragma unroll
      for (int mt = 0; mt < 2; ++mt)
#pragma unroll
        for (int nt = 0; nt < 4; ++nt)
          acc[mt][nt] = __builtin_amdgcn_mfma_f32_16x16x32_f16(av[mt], bv[nt], acc[mt][nt], 0, 0, 0);
    }
    buf ^= 1;
  }

  // epilogue: bias + (i,f,g,o) shfl-gather + cell update
  const int base = l & ~3;
  const int gsel = l & 3;
#pragma unroll
  for (int nt = 0; nt < 4; ++nt) {
    const int ncol = N0 + wn * 64 + nt * 16 + fr;
    const float bc = bp[ncol];
    const int jg = ncol >> 2;
#pragma unroll
    for (int mt = 0; mt < 2; ++mt) {
#pragma unroll
      for (int r = 0; r < 4; ++r) {
        float v = acc[mt][nt][r] + bc;
        float gi = __shfl(v, base + 0);
        float gf = __shfl(v, base + 1);
        float gg = __shfl(v, base + 2);
        float go = __shfl(v, base + 3);
        const int mg = M0 + wm * 32 + mt * 16 + q * 4 + r;
        const size_t cidx = (size_t)mg * H_ + jg;
        const float cold = cio[cidx];
        const float cn = fast_sig(gf) * cold + fast_sig(gi) * fast_tanh(gg);
        const float hn = fast_sig(go) * fast_tanh(cn);
        if (gsel == 0) hout[cidx] = (half_t)hn;
        else if (gsel == 1) cio[cidx] = cn;
      }
    }
  }
}

// ---------------- the persistent kernel ----------------

__global__ __launch_bounds__(256, 1)
void k_seq(const half_t* __restrict__ xf,
           const half_t* __restrict__ Wp0e, const float* __restrict__ bp0e,
           const half_t* __restrict__ Wp1e, const float* __restrict__ bp1e,
           const half_t* __restrict__ Wp0d, const float* __restrict__ bp0d,
           const half_t* __restrict__ Wp1d, const float* __restrict__ bp1d,
           half_t* __restrict__ h0, half_t* __restrict__ h1,
           float* __restrict__ c0, float* __restrict__ c1,
           half_t* __restrict__ dpad,
           const float* __restrict__ Wfc, const float* __restrict__ bfc,
           float* __restrict__ out,
           int* __restrict__ fh0, int* __restrict__ fh1, int* __restrict__ ffc) {
  __shared__ __align__(16) half_t ldsA[2 * 64 * 64];    // 16 KB
  __shared__ __align__(16) half_t ldsB[2 * 128 * 64];   // 32 KB

  const int tid = threadIdx.x;
  const int bid = blockIdx.x;
  // XCD-aware: same-N (same weight slab) WGs cluster per XCD
  const int n = 2 * (bid & 7) + ((bid >> 3) & 1);
  const int m = bid >> 4;
  const int M0 = m * 64, N0 = n * 128;

  half_t* h0s[3] = {h0, h0 + BH_, h0 + 2 * BH_};
  half_t* h1s[3] = {h1, h1 + BH_, h1 + 2 * BH_};

  // -------- encoder: phase u does L0e(u) || L1e(u-1) --------
  for (int u = 0; u <= S_; ++u) {
    if (tid == 0) {
      if (u >= 1) wait_ge(fh0 + (u + 1) * 16 + m, 16);   // h0(u-1)
      if (u >= 2) wait_ge(fh1 + u * 16 + m, 16);         // h1(u-2)
    }
    __syncthreads();
    const int sp = (u + 2) % 3, scur = u % 3, spp = (u + 1) % 3;
    if (u < S_) {
      gemm_cell(ldsA, ldsB, true,
                xf + ((size_t)u * B_ + M0) * 64, 64,
                h0s[sp] + (size_t)M0 * H_, (const half_t*)0,
                Wp0e + (size_t)N0 * 576, 576, 9,
                bp0e, c0, h0s[scur], M0, N0);
      __syncthreads();
      if (tid == 0) bump(fh0 + (u + 2) * 16 + m);
    }
    if (u >= 1) {
      gemm_cell(ldsA, ldsB, false, (const half_t*)0, 0,
                h0s[sp] + (size_t)M0 * H_, h1s[spp] + (size_t)M0 * H_,
                Wp1e + (size_t)N0 * 1024, 1024, 16,
                bp1e, c1, h1s[sp], M0, N0);
      __syncthreads();
      if (tid == 0) bump(fh1 + (u + 1) * 16 + m);
    }
  }

  // -------- decoder --------
  for (int t = 0; t < HOR_; ++t) {
    const int u = S_ + t;
    if (tid == 0) {
      wait_ge(fh0 + (u + 1) * 16 + m, 16);               // h0(u-1)
      wait_ge(fh1 + (u + 1) * 16 + m, 16);               // h1(u-1)
      if (t >= 1) wait_ge(ffc + (t - 1) * 16 + m, 1);    // dpad(t)
    }
    __syncthreads();
    const int sp = (u + 2) % 3, scur = u % 3;
    gemm_cell(ldsA, ldsB, true,
              dpad + (size_t)M0 * 64, 64,
              h0s[sp] + (size_t)M0 * H_, (const half_t*)0,
              Wp0d + (size_t)N0 * 576, 576, 9,
              bp0d, c0, h0s[scur], M0, N0);
    __syncthreads();
    if (tid == 0) {
      bump(fh0 + (u + 2) * 16 + m);
      wait_ge(fh0 + (u + 2) * 16 + m, 16);               // all of h0(t)
    }
    __syncthreads();
    gemm_cell(ldsA, ldsB, false, (const half_t*)0, 0,
              h0s[scur] + (size_t)M0 * H_, h1s[sp] + (size_t)M0 * H_,
              Wp1d + (size_t)N0 * 1024, 1024, 16,
              bp1d, c1, h1s[scur], M0, N0);
    __syncthreads();
    if (tid == 0) bump(fh1 + (u + 2) * 16 + m);
    if (n == 0) {                                        // WG (m,0): FC + feedback
      if (tid == 0) wait_ge(fh1 + (u + 2) * 16 + m, 16);
      __syncthreads();
#pragma unroll
      for (int it = 0; it < 2; ++it) {
        int idx = tid + it * 256;
        int r = idx >> 3, cc = idx & 7;
        const half_t* hr = h1s[scur] + (size_t)(M0 + r) * H_;
        const float* wr = Wfc + cc * H_;
        float s = bfc[cc];
        for (int k8 = 0; k8 < H_ / 8; ++k8) {
          half8 hv = *(const half8*)(hr + k8 * 8);
#pragma unroll
          for (int e = 0; e < 8; ++e) s += (float)hv[e] * wr[k8 * 8 + e];
        }
        out[((size_t)(M0 + r) * HOR_ + t) * NT_ + cc] = s;
        dpad[(M0 + r) * 64 + cc] = (half_t)s;
      }
      __syncthreads();
      if (tid == 0) bump(ffc + t * 16 + m);
    }
  }
}

// ---------------- host ----------------

extern "C" void kernel_launch(void* const* d_in, const int* in_sizes, int n_in,
                              void* d_out, int out_size, void* d_ws, size_t ws_size,
                              hipStream_t stream) {
  (void)in_sizes; (void)n_in; (void)out_size; (void)ws_size;
  const float* x     = (const float*)d_in[0];
  const float* Wih0e = (const float*)d_in[1];
  const float* Whh0e = (const float*)d_in[2];
  const float* b0e   = (const float*)d_in[3];
  const float* Wih1e = (const float*)d_in[4];
  const float* Whh1e = (const float*)d_in[5];
  const float* b1e   = (const float*)d_in[6];
  const float* Wih0d = (const float*)d_in[7];
  const float* Whh0d = (const float*)d_in[8];
  const float* b0d   = (const float*)d_in[9];
  const float* Wih1d = (const float*)d_in[10];
  const float* Whh1d = (const float*)d_in[11];
  const float* b1d   = (const float*)d_in[12];
  const float* Wfc   = (const float*)d_in[13];
  const float* bfc   = (const float*)d_in[14];
  float* out = (float*)d_out;

  char* p = (char*)d_ws;
  auto alloc = [&](size_t bytes) {
    char* r = p;
    p += (bytes + 255) & ~(size_t)255;
    return r;
  };
  half_t* xf   = (half_t*)alloc((size_t)S_ * B_ * 64 * 2);
  half_t* Wp0e = (half_t*)alloc((size_t)NG_ * 576 * 2);
  half_t* Wp1e = (half_t*)alloc((size_t)NG_ * 1024 * 2);
  half_t* Wp0d = (half_t*)alloc((size_t)NG_ * 576 * 2);
  half_t* Wp1d = (half_t*)alloc((size_t)NG_ * 1024 * 2);
  float*  bp0e = (float*)alloc(NG_ * 4);
  float*  bp1e = (float*)alloc(NG_ * 4);
  float*  bp0d = (float*)alloc(NG_ * 4);
  float*  bp1d = (float*)alloc(NG_ * 4);
  half_t* h0   = (half_t*)alloc((size_t)3 * BH_ * 2);
  half_t* h1   = (half_t*)alloc((size_t)3 * BH_ * 2);
  float*  c0   = (float*)alloc((size_t)BH_ * 4);
  float*  c1   = (float*)alloc((size_t)BH_ * 4);
  half_t* dpad = (half_t*)alloc((size_t)B_ * 64 * 2);
  int*    fh0  = (int*)alloc(384 * 16 * 4);
  int*    fh1  = (int*)alloc(384 * 16 * 4);
  int*    ffc  = (int*)alloc(32 * 16 * 4);

  k_xT<<<(S_ * B_ * 64) / 256, 256, 0, stream>>>(x, xf);
  k_pack<<<(NG_ * 576) / 256, 256, 0, stream>>>(Wih0e, Whh0e, b0e, Wp0e, bp0e, 64, 64, 576);
  k_pack<<<(NG_ * 1024) / 256, 256, 0, stream>>>(Wih1e, Whh1e, b1e, Wp1e, bp1e, 512, 512, 1024);
  k_pack<<<(NG_ * 576) / 256, 256, 0, stream>>>(Wih0d, Whh0d, b0d, Wp0d, bp0d, 8, 64, 576);
  k_pack<<<(NG_ * 1024) / 256, 256, 0, stream>>>(Wih1d, Whh1d, b1d, Wp1d, bp1d, 512, 512, 1024);
  k_init<<<BH_ / 256, 256, 0, stream>>>(c0, c1, h0, h1, dpad, fh0, fh1, ffc);

  k_seq<<<256, 256, 0, stream>>>(xf, Wp0e, bp0e, Wp1e, bp1e, Wp0d, bp0d, Wp1d, bp1d,
                                 h0, h1, c0, c1, dpad, Wfc, bfc, out, fh0, fh1, ffc);
}

// Round 6
// 12681.578 us; speedup vs baseline: 1.4320x; 1.4320x over previous
//
#include <hip/hip_runtime.h>

// ---------------------------------------------------------------------------
// Persistent-kernel Seq2Seq LSTM, cross-XCD dataflow via relaxed SYSTEM-scope
// atomics (sc0 sc1: bypass L1+L2 -> coherent at Infinity Fabric).
// History: R3 acquire/release flags -> buffer_inv per poll -> L2 never warm
// (18ms). R4 relaxed AGENT atomics -> sc0 only -> cross-XCD stale (1.3e-2).
// R5 inline-asm sc0sc1 loads -> untracked by waitcnt pass -> spilled asm-dest
// regs read before load landed -> NaN. R6: relaxed SYSTEM atomics: correct
// bits AND fully compiler-tracked (safe under spills). No inline asm at all.
//   - private data (weights, c, bias, xf): normal cached path, L2 stays warm
//   - shared data (h0/h1/dpad) + flags: relaxed system atomics
//   - ordering: __syncthreads' vmcnt(0) drain before each flag bump
// ---------------------------------------------------------------------------

typedef _Float16 half_t;
typedef _Float16 half8 __attribute__((ext_vector_type(8)));
typedef _Float16 half4 __attribute__((ext_vector_type(4)));
typedef float floatx4 __attribute__((ext_vector_type(4)));
typedef unsigned long long u64;

#define B_ 1024
#define S_ 256
#define IN_ 64
#define H_ 512
#define NT_ 8
#define HOR_ 24
#define NG_ 2048       // 4*H
#define BH_ (B_ * H_)

__device__ __forceinline__ void async_cp16(const void* g, void* l) {
  __builtin_amdgcn_global_load_lds((const __attribute__((address_space(1))) void*)g,
                                   (__attribute__((address_space(3))) void*)l,
                                   16, 0, 0);
}

__device__ __forceinline__ float fast_sig(float x) {
  return __builtin_amdgcn_rcpf(1.0f + __builtin_amdgcn_exp2f(-1.44269504f * x));
}
__device__ __forceinline__ float fast_tanh(float x) {
  float xx = fminf(10.0f, fmaxf(-10.0f, x));
  float e = __builtin_amdgcn_exp2f(2.88539008f * xx);
  return (e - 1.0f) * __builtin_amdgcn_rcpf(e + 1.0f);
}

// relaxed SYSTEM-scope = sc0 sc1 (IF-coherent), tracked, no cache maintenance
__device__ __forceinline__ u64 sys_ld8(const void* p) {
  return __hip_atomic_load((const u64*)p, __ATOMIC_RELAXED, __HIP_MEMORY_SCOPE_SYSTEM);
}
__device__ __forceinline__ void sys_st8(void* p, u64 v) {
  __hip_atomic_store((u64*)p, v, __ATOMIC_RELAXED, __HIP_MEMORY_SCOPE_SYSTEM);
}
__device__ __forceinline__ void sys_st4(void* p, unsigned v) {
  __hip_atomic_store((unsigned*)p, v, __ATOMIC_RELAXED, __HIP_MEMORY_SCOPE_SYSTEM);
}
__device__ __forceinline__ void wait_ge(const int* f, int tgt) {
  while (__hip_atomic_load(f, __ATOMIC_RELAXED, __HIP_MEMORY_SCOPE_SYSTEM) < tgt)
    __builtin_amdgcn_s_sleep(1);
}
__device__ __forceinline__ void bump(int* f) {
  // preceding __syncthreads drained vmcnt(0) -> our sc0sc1 stores are at IF
  __hip_atomic_fetch_add(f, 1, __ATOMIC_RELAXED, __HIP_MEMORY_SCOPE_SYSTEM);
}

// ---------------- setup kernels ----------------

__global__ void k_xT(const float* __restrict__ x, half_t* __restrict__ xf) {
  int i = blockIdx.x * 256 + threadIdx.x;  // (t*B + b)*64 + e
  int e = i & 63;
  int tb = i >> 6;
  int t = tb >> 10;
  int b = tb & 1023;
  xf[i] = (half_t)x[((size_t)b * S_ + t) * 64 + e];
}

__global__ void k_pack(const float* __restrict__ Wih, const float* __restrict__ Whh,
                       const float* __restrict__ bias,
                       half_t* __restrict__ Wp, float* __restrict__ bp,
                       int K0real, int K0pad, int K) {
  int i = blockIdx.x * 256 + threadIdx.x;
  if (i >= NG_ * K) return;
  int r = i / K;
  int k = i - r * K;
  int j = r >> 2, g = r & 3;
  int src = g * H_ + j;
  float v;
  if (k < K0pad) v = (k < K0real) ? Wih[src * K0real + k] : 0.0f;
  else           v = Whh[src * H_ + (k - K0pad)];
  Wp[i] = (half_t)v;
  if (k == 0) bp[r] = bias[src];
}

__global__ void k_init(float* c0, float* c1, half_t* h0, half_t* h1, half_t* dpad,
                       int* fh0, int* fh1, int* ffc) {
  int i = blockIdx.x * 256 + threadIdx.x;
  if (i < BH_) {
    c0[i] = 0.0f; c1[i] = 0.0f;
    h0[i] = (half_t)0.0f; h0[i + BH_] = (half_t)0.0f; h0[i + 2 * BH_] = (half_t)0.0f;
    h1[i] = (half_t)0.0f; h1[i + BH_] = (half_t)0.0f; h1[i + 2 * BH_] = (half_t)0.0f;
  }
  if (i < B_ * 64) dpad[i] = (half_t)0.0f;
  if (i < 384 * 16) { int v = (i < 32) ? 16 : 0; fh0[i] = v; fh1[i] = v; }
  if (i < 32 * 16) ffc[i] = 0;
}

// ---------------- fused GEMM + LSTM-cell (device) ----------------
// WG tile 64(M) x 128(N gates), 4 waves, wave tile 32x64. BK=64 chunks,
// double-buffered LDS. B (weights): global_load_lds from warm L2.
// A (h/dpad): system-scope 8B loads -> regs (1-chunk pipeline) -> ds_write.
// A chunk0 for encoder (xf): normal cached loads (kernel-input, read-only).

__device__ __forceinline__ void gemm_cell(
    half_t* ldsA, half_t* ldsB, half_t* ldsH, bool mode0, bool sysA0,
    const half_t* s0, int str0, const half_t* sA, const half_t* sB,
    const half_t* __restrict__ Bs, int K, int NC,
    const float* __restrict__ bp, float* __restrict__ cio,
    half_t* __restrict__ hout, int M0, int N0) {
  const int tid = threadIdx.x;
  const int l = tid & 63, w = tid >> 6;
  const int wm = w >> 1, wn = w & 1;
  const int fr = l & 15, q = l >> 4;
  const int r8 = l >> 3, c8 = l & 7;

  floatx4 acc[2][4];
#pragma unroll
  for (int a = 0; a < 2; ++a)
#pragma unroll
    for (int b = 0; b < 4; ++b) acc[a][b] = (floatx4){0.f, 0.f, 0.f, 0.f};

  auto issue_A = [&](int c, u64 (&ar)[2][2]) {
    const half_t* base; int str; bool sys;
    if (mode0) {
      if (c == 0) { base = s0; str = str0; sys = sysA0; }
      else        { base = sA + (size_t)(c - 1) * 64; str = H_; sys = true; }
    } else {
      base = (c < 8) ? sA + (size_t)c * 64 : sB + (size_t)(c - 8) * 64;
      str = H_; sys = true;
    }
#pragma unroll
    for (int ii = 0; ii < 2; ++ii) {
      int i = 2 * w + ii;
      int r = 8 * i + r8;
      int sc = c8 ^ r8;
      const half_t* p = base + (size_t)r * str + sc * 8;
      if (sys) {
        ar[ii][0] = sys_ld8(p);
        ar[ii][1] = sys_ld8(p + 4);
      } else {
        ar[ii][0] = ((const u64*)p)[0];
        ar[ii][1] = ((const u64*)p)[1];
      }
    }
  };
  auto write_A = [&](int buf, u64 (&ar)[2][2]) {
    half_t* la = ldsA + buf * 4096;
#pragma unroll
    for (int ii = 0; ii < 2; ++ii) {
      int i = 2 * w + ii;
      u64* d = (u64*)(la + i * 512 + 64 * r8 + 8 * c8);
      d[0] = ar[ii][0];
      d[1] = ar[ii][1];
    }
  };
  auto stage_B = [&](int c, int buf) {
    half_t* lb = ldsB + buf * 8192;
    const half_t* bsrc = Bs + (size_t)c * 64;
#pragma unroll
    for (int jj = 0; jj < 4; ++jj) {
      int j = 4 * w + jj;
      int r = 8 * j + r8;
      int sc = c8 ^ r8;
      async_cp16(bsrc + (size_t)r * K + sc * 8, lb + j * 512);
    }
  };

  u64 ar[2][2][2];
  issue_A(0, ar[0]);
  write_A(0, ar[0]);     // compiler inserts the vmcnt wait (tracked loads)
  stage_B(0, 0);
  issue_A(1, ar[1]);
  int buf = 0;
  for (int c = 0; c < NC; ++c) {
    __syncthreads();     // vmcnt(0) drain: buf B staged, prefetched A in regs
    if (c + 1 < NC) {
      write_A(buf ^ 1, ar[(c + 1) & 1]);
      stage_B(c + 1, buf ^ 1);
    }
    if (c + 2 < NC) issue_A(c + 2, ar[c & 1]);
    const half_t* la = ldsA + buf * 4096;
    const half_t* lb = ldsB + buf * 8192;
#pragma unroll
    for (int kk = 0; kk < 2; ++kk) {
      half8 av[2], bv[4];
#pragma unroll
      for (int mt = 0; mt < 2; ++mt) {
        int r = wm * 32 + mt * 16 + fr;
        int sc = (4 * kk + q) ^ (fr & 7);
        av[mt] = *(const half8*)(la + r * 64 + sc * 8);
      }
#pragma unroll
      for (int nt = 0; nt < 4; ++nt) {
        int r = wn * 64 + nt * 16 + fr;
        int sc = (4 * kk + q) ^ (fr & 7);
        bv[nt] = *(const half8*)(lb + r * 64 + sc * 8);
      }
#pragma unroll
      for (int mt = 0; mt < 2; ++mt)
#pragma unroll
        for (int nt = 0; nt < 4; ++nt)
          acc[mt][nt] = __builtin_amdgcn_mfma_f32_16x16x32_f16(av[mt], bv[nt], acc[mt][nt], 0, 0, 0);
    }
    buf ^= 1;
  }

  // epilogue: bias + (i,f,g,o) shfl-gather + cell update; h via dedicated
  // ldsH, then wide system-scope stores.
  const int base = l & ~3;
  const int gsel = l & 3;
#pragma unroll
  for (int nt = 0; nt < 4; ++nt) {
    const int ncl = wn * 64 + nt * 16 + fr;   // local gate col
    const float bc = bp[N0 + ncl];
    const int lc = ncl >> 2;                  // local cell col 0..31
    const int jg = (N0 + ncl) >> 2;           // global cell col
#pragma unroll
    for (int mt = 0; mt < 2; ++mt) {
#pragma unroll
      for (int r = 0; r < 4; ++r) {
        float v = acc[mt][nt][r] + bc;
        float gi = __shfl(v, base + 0);
        float gf = __shfl(v, base + 1);
        float gg = __shfl(v, base + 2);
        float go = __shfl(v, base + 3);
        const int lm = wm * 32 + mt * 16 + q * 4 + r;
        const size_t cidx = (size_t)(M0 + lm) * H_ + jg;
        const float cold = cio[cidx];
        const float cn = fast_sig(gf) * cold + fast_sig(gi) * fast_tanh(gg);
        const float hn = fast_sig(go) * fast_tanh(cn);
        if (gsel == 0) ldsH[lm * 32 + lc] = (half_t)hn;
        else if (gsel == 1) cio[cidx] = cn;
      }
    }
  }
  __syncthreads();
  {
    const int tr = tid >> 2, cg = tid & 3;
    const u64* lp = (const u64*)(ldsH + tr * 32 + cg * 8);
    half_t* dst = hout + (size_t)(M0 + tr) * H_ + (N0 >> 2) + cg * 8;
    sys_st8(dst, lp[0]);
    sys_st8(dst + 4, lp[1]);
  }
}

// ---------------- the persistent kernel ----------------

__global__ __launch_bounds__(256, 1)
void k_seq(const half_t* __restrict__ xf,
           const half_t* __restrict__ Wp0e, const float* __restrict__ bp0e,
           const half_t* __restrict__ Wp1e, const float* __restrict__ bp1e,
           const half_t* __restrict__ Wp0d, const float* __restrict__ bp0d,
           const half_t* __restrict__ Wp1d, const float* __restrict__ bp1d,
           half_t* __restrict__ h0, half_t* __restrict__ h1,
           float* __restrict__ c0, float* __restrict__ c1,
           half_t* __restrict__ dpad,
           const float* __restrict__ Wfc, const float* __restrict__ bfc,
           float* __restrict__ out,
           int* __restrict__ fh0, int* __restrict__ fh1, int* __restrict__ ffc) {
  __shared__ __align__(16) half_t ldsA[2 * 64 * 64];    // 16 KB
  __shared__ __align__(16) half_t ldsB[2 * 128 * 64];   // 32 KB
  __shared__ __align__(16) half_t ldsH[64 * 32];        // 4 KB (dedicated)

  const int tid = threadIdx.x;
  const int bid = blockIdx.x;
  // same-n clustering per XCD: weight slab (~820KB/XCD) stays L2-resident
  const int n = 2 * (bid & 7) + ((bid >> 3) & 1);
  const int m = bid >> 4;
  const int M0 = m * 64, N0 = n * 128;

  half_t* h0s[3] = {h0, h0 + BH_, h0 + 2 * BH_};
  half_t* h1s[3] = {h1, h1 + BH_, h1 + 2 * BH_};

  // -------- encoder: phase u does L0e(u) || L1e(u-1) --------
  for (int u = 0; u <= S_; ++u) {
    if (tid == 0) {
      if (u >= 1) wait_ge(fh0 + (u + 1) * 16 + m, 16);   // h0(u-1)
      if (u >= 2) wait_ge(fh1 + u * 16 + m, 16);         // h1(u-2)
    }
    __syncthreads();
    const int sp = (u + 2) % 3, scur = u % 3, spp = (u + 1) % 3;
    if (u < S_) {
      gemm_cell(ldsA, ldsB, ldsH, true, false,
                xf + ((size_t)u * B_ + M0) * 64, 64,
                h0s[sp] + (size_t)M0 * H_, (const half_t*)0,
                Wp0e + (size_t)N0 * 576, 576, 9,
                bp0e, c0, h0s[scur], M0, N0);
      __syncthreads();                                   // drains sys stores
      if (tid == 0) bump(fh0 + (u + 2) * 16 + m);
    }
    if (u >= 1) {
      gemm_cell(ldsA, ldsB, ldsH, false, false, (const half_t*)0, 0,
                h0s[sp] + (size_t)M0 * H_, h1s[spp] + (size_t)M0 * H_,
                Wp1e + (size_t)N0 * 1024, 1024, 16,
                bp1e, c1, h1s[sp], M0, N0);
      __syncthreads();
      if (tid == 0) bump(fh1 + (u + 1) * 16 + m);
    }
  }

  // -------- decoder --------
  for (int t = 0; t < HOR_; ++t) {
    const int u = S_ + t;
    if (tid == 0) {
      wait_ge(fh0 + (u + 1) * 16 + m, 16);               // h0(u-1)
      wait_ge(fh1 + (u + 1) * 16 + m, 16);               // h1(u-1)
      if (t >= 1) wait_ge(ffc + (t - 1) * 16 + m, 1);    // dpad(t)
    }
    __syncthreads();
    const int sp = (u + 2) % 3, scur = u % 3;
    gemm_cell(ldsA, ldsB, ldsH, true, true,
              dpad + (size_t)M0 * 64, 64,
              h0s[sp] + (size_t)M0 * H_, (const half_t*)0,
              Wp0d + (size_t)N0 * 576, 576, 9,
              bp0d, c0, h0s[scur], M0, N0);
    __syncthreads();
    if (tid == 0) {
      bump(fh0 + (u + 2) * 16 + m);
      wait_ge(fh0 + (u + 2) * 16 + m, 16);               // all of h0(t)
    }
    __syncthreads();
    gemm_cell(ldsA, ldsB, ldsH, false, false, (const half_t*)0, 0,
              h0s[scur] + (size_t)M0 * H_, h1s[sp] + (size_t)M0 * H_,
              Wp1d + (size_t)N0 * 1024, 1024, 16,
              bp1d, c1, h1s[scur], M0, N0);
    __syncthreads();
    if (tid == 0) bump(fh1 + (u + 2) * 16 + m);
    if (n == 0) {                                        // WG (m,0): FC + feedback
      if (tid == 0) wait_ge(fh1 + (u + 2) * 16 + m, 16);
      __syncthreads();
      for (int half = 0; half < 2; ++half) {
        // stage 32 h1 rows (32 KB) into ldsB via system loads
#pragma unroll
        for (int i = 0; i < 16; ++i) {
          int li = tid * 16 + i;                 // 0..4095
          int rr = li >> 7, ee = li & 127;       // row 0..31, 8B-chunk 0..127
          ((u64*)ldsB)[li] =
              sys_ld8(h1s[scur] + (size_t)(M0 + half * 32 + rr) * H_ + ee * 4);
        }
        __syncthreads();
        const int r = tid >> 3, cc = tid & 7;
        const int rowg = M0 + half * 32 + r;
        const half_t* hl = ldsB + r * 512;
        const float* wr = Wfc + cc * H_;
        float s = bfc[cc];
#pragma unroll 8
        for (int k8 = 0; k8 < H_ / 8; ++k8) {
          half8 hv = *(const half8*)(hl + k8 * 8);
#pragma unroll
          for (int e = 0; e < 8; ++e) s += (float)hv[e] * wr[k8 * 8 + e];
        }
        out[((size_t)rowg * HOR_ + t) * NT_ + cc] = s;
        float sn = __shfl(s, (tid & 63) + 1);            // pair-neighbor
        if (!(cc & 1)) {
          unsigned pk = (unsigned)__builtin_bit_cast(unsigned short, (half_t)s)
                      | ((unsigned)__builtin_bit_cast(unsigned short, (half_t)sn) << 16);
          sys_st4(dpad + rowg * 64 + cc, pk);
        }
        __syncthreads();
      }
      if (tid == 0) bump(ffc + t * 16 + m);
    }
  }
}

// ---------------- host ----------------

extern "C" void kernel_launch(void* const* d_in, const int* in_sizes, int n_in,
                              void* d_out, int out_size, void* d_ws, size_t ws_size,
                              hipStream_t stream) {
  (void)in_sizes; (void)n_in; (void)out_size; (void)ws_size;
  const float* x     = (const float*)d_in[0];
  const float* Wih0e = (const float*)d_in[1];
  const float* Whh0e = (const float*)d_in[2];
  const float* b0e   = (const float*)d_in[3];
  const float* Wih1e = (const float*)d_in[4];
  const float* Whh1e = (const float*)d_in[5];
  const float* b1e   = (const float*)d_in[6];
  const float* Wih0d = (const float*)d_in[7];
  const float* Whh0d = (const float*)d_in[8];
  const float* b0d   = (const float*)d_in[9];
  const float* Wih1d = (const float*)d_in[10];
  const float* Whh1d = (const float*)d_in[11];
  const float* b1d   = (const float*)d_in[12];
  const float* Wfc   = (const float*)d_in[13];
  const float* bfc   = (const float*)d_in[14];
  float* out = (float*)d_out;

  char* p = (char*)d_ws;
  auto alloc = [&](size_t bytes) {
    char* r = p;
    p += (bytes + 255) & ~(size_t)255;
    return r;
  };
  half_t* xf   = (half_t*)alloc((size_t)S_ * B_ * 64 * 2);
  half_t* Wp0e = (half_t*)alloc((size_t)NG_ * 576 * 2);
  half_t* Wp1e = (half_t*)alloc((size_t)NG_ * 1024 * 2);
  half_t* Wp0d = (half_t*)alloc((size_t)NG_ * 576 * 2);
  half_t* Wp1d = (half_t*)alloc((size_t)NG_ * 1024 * 2);
  float*  bp0e = (float*)alloc(NG_ * 4);
  float*  bp1e = (float*)alloc(NG_ * 4);
  float*  bp0d = (float*)alloc(NG_ * 4);
  float*  bp1d = (float*)alloc(NG_ * 4);
  half_t* h0   = (half_t*)alloc((size_t)3 * BH_ * 2);
  half_t* h1   = (half_t*)alloc((size_t)3 * BH_ * 2);
  float*  c0   = (float*)alloc((size_t)BH_ * 4);
  float*  c1   = (float*)alloc((size_t)BH_ * 4);
  half_t* dpad = (half_t*)alloc((size_t)B_ * 64 * 2);
  int*    fh0  = (int*)alloc(384 * 16 * 4);
  int*    fh1  = (int*)alloc(384 * 16 * 4);
  int*    ffc  = (int*)alloc(32 * 16 * 4);

  k_xT<<<(S_ * B_ * 64) / 256, 256, 0, stream>>>(x, xf);
  k_pack<<<(NG_ * 576) / 256, 256, 0, stream>>>(Wih0e, Whh0e, b0e, Wp0e, bp0e, 64, 64, 576);
  k_pack<<<(NG_ * 1024) / 256, 256, 0, stream>>>(Wih1e, Whh1e, b1e, Wp1e, bp1e, 512, 512, 1024);
  k_pack<<<(NG_ * 576) / 256, 256, 0, stream>>>(Wih0d, Whh0d, b0d, Wp0d, bp0d, 8, 64, 576);
  k_pack<<<(NG_ * 1024) / 256, 256, 0, stream>>>(Wih1d, Whh1d, b1d, Wp1d, bp1d, 512, 512, 1024);
  k_init<<<BH_ / 256, 256, 0, stream>>>(c0, c1, h0, h1, dpad, fh0, fh1, ffc);

  k_seq<<<256, 256, 0, stream>>>(xf, Wp0e, bp0e, Wp1e, bp1e, Wp0d, bp0d, Wp1d, bp1d,
                                 h0, h1, c0, c1, dpad, Wfc, bfc, out, fh0, fh1, ffc);
}

// Round 7
// 10193.095 us; speedup vs baseline: 1.7816x; 1.2441x over previous
//
#include <hip/hip_runtime.h>

// ---------------------------------------------------------------------------
// Persistent-kernel Seq2Seq LSTM, cross-XCD dataflow via relaxed SYSTEM-scope
// atomics (verified correct in R6). R7 changes (perf only, structure kept):
//  1. Cell state c0/c1 moved from global fp32 (4MB/step through L2 -> evicted
//     the weight set every phase, FETCH 2.7GB) into REGISTERS: each WG owns a
//     fixed 64x32 cell tile; per 4-lane group the lane with gsel==r keeps c
//     for sub-row r (8 floats/thread/layer), handed out via __shfl.
//  2. A-path LDS store as single ds_write_b128 (was 2x b64 with 8-way bank
//     conflict: row stride 128B == 32 banks).
//  3. A sys-loads for chunk c+2 issued before ds_writes of c+1.
// ---------------------------------------------------------------------------

typedef _Float16 half_t;
typedef _Float16 half8 __attribute__((ext_vector_type(8)));
typedef float floatx4 __attribute__((ext_vector_type(4)));
typedef unsigned long long u64;
typedef u64 u64x2 __attribute__((ext_vector_type(2)));

#define B_ 1024
#define S_ 256
#define IN_ 64
#define H_ 512
#define NT_ 8
#define HOR_ 24
#define NG_ 2048       // 4*H
#define BH_ (B_ * H_)

__device__ __forceinline__ void async_cp16(const void* g, void* l) {
  __builtin_amdgcn_global_load_lds((const __attribute__((address_space(1))) void*)g,
                                   (__attribute__((address_space(3))) void*)l,
                                   16, 0, 0);
}

__device__ __forceinline__ float fast_sig(float x) {
  return __builtin_amdgcn_rcpf(1.0f + __builtin_amdgcn_exp2f(-1.44269504f * x));
}
__device__ __forceinline__ float fast_tanh(float x) {
  float xx = fminf(10.0f, fmaxf(-10.0f, x));
  float e = __builtin_amdgcn_exp2f(2.88539008f * xx);
  return (e - 1.0f) * __builtin_amdgcn_rcpf(e + 1.0f);
}

// relaxed SYSTEM-scope = sc0 sc1 (IF-coherent), tracked, no cache maintenance
__device__ __forceinline__ u64 sys_ld8(const void* p) {
  return __hip_atomic_load((const u64*)p, __ATOMIC_RELAXED, __HIP_MEMORY_SCOPE_SYSTEM);
}
__device__ __forceinline__ void sys_st8(void* p, u64 v) {
  __hip_atomic_store((u64*)p, v, __ATOMIC_RELAXED, __HIP_MEMORY_SCOPE_SYSTEM);
}
__device__ __forceinline__ void sys_st4(void* p, unsigned v) {
  __hip_atomic_store((unsigned*)p, v, __ATOMIC_RELAXED, __HIP_MEMORY_SCOPE_SYSTEM);
}
__device__ __forceinline__ void wait_ge(const int* f, int tgt) {
  while (__hip_atomic_load(f, __ATOMIC_RELAXED, __HIP_MEMORY_SCOPE_SYSTEM) < tgt)
    __builtin_amdgcn_s_sleep(1);
}
__device__ __forceinline__ void bump(int* f) {
  // preceding __syncthreads drained vmcnt(0) -> our sc0sc1 stores are at IF
  __hip_atomic_fetch_add(f, 1, __ATOMIC_RELAXED, __HIP_MEMORY_SCOPE_SYSTEM);
}

// ---------------- setup kernels ----------------

__global__ void k_xT(const float* __restrict__ x, half_t* __restrict__ xf) {
  int i = blockIdx.x * 256 + threadIdx.x;  // (t*B + b)*64 + e
  int e = i & 63;
  int tb = i >> 6;
  int t = tb >> 10;
  int b = tb & 1023;
  xf[i] = (half_t)x[((size_t)b * S_ + t) * 64 + e];
}

__global__ void k_pack(const float* __restrict__ Wih, const float* __restrict__ Whh,
                       const float* __restrict__ bias,
                       half_t* __restrict__ Wp, float* __restrict__ bp,
                       int K0real, int K0pad, int K) {
  int i = blockIdx.x * 256 + threadIdx.x;
  if (i >= NG_ * K) return;
  int r = i / K;
  int k = i - r * K;
  int j = r >> 2, g = r & 3;
  int src = g * H_ + j;
  float v;
  if (k < K0pad) v = (k < K0real) ? Wih[src * K0real + k] : 0.0f;
  else           v = Whh[src * H_ + (k - K0pad)];
  Wp[i] = (half_t)v;
  if (k == 0) bp[r] = bias[src];
}

__global__ void k_init(half_t* h0, half_t* h1, half_t* dpad,
                       int* fh0, int* fh1, int* ffc) {
  int i = blockIdx.x * 256 + threadIdx.x;
  if (i < BH_) {
    h0[i] = (half_t)0.0f; h0[i + BH_] = (half_t)0.0f; h0[i + 2 * BH_] = (half_t)0.0f;
    h1[i] = (half_t)0.0f; h1[i + BH_] = (half_t)0.0f; h1[i + 2 * BH_] = (half_t)0.0f;
  }
  if (i < B_ * 64) dpad[i] = (half_t)0.0f;
  if (i < 384 * 16) { int v = (i < 32) ? 16 : 0; fh0[i] = v; fh1[i] = v; }
  if (i < 32 * 16) ffc[i] = 0;
}

// ---------------- fused GEMM + LSTM-cell (device) ----------------
// WG tile 64(M) x 128(N gates), 4 waves, wave tile 32x64. BK=64 chunks,
// double-buffered LDS. B (weights): global_load_lds from warm L2.
// A (h/dpad): system-scope 8B loads -> regs (pipelined) -> ds_write_b128.
// c: creg[8] per thread (gsel==r lane keeps sub-row r of each (nt,mt) tile).

__device__ __forceinline__ void gemm_cell(
    half_t* ldsA, half_t* ldsB, half_t* ldsH, bool mode0, bool sysA0,
    const half_t* s0, int str0, const half_t* sA, const half_t* sB,
    const half_t* __restrict__ Bs, int K, int NC,
    const float* __restrict__ bp, float* creg,
    half_t* __restrict__ hout, int M0, int N0) {
  const int tid = threadIdx.x;
  const int l = tid & 63, w = tid >> 6;
  const int wm = w >> 1, wn = w & 1;
  const int fr = l & 15, q = l >> 4;
  const int r8 = l >> 3, c8 = l & 7;

  floatx4 acc[2][4];
#pragma unroll
  for (int a = 0; a < 2; ++a)
#pragma unroll
    for (int b = 0; b < 4; ++b) acc[a][b] = (floatx4){0.f, 0.f, 0.f, 0.f};

  auto issue_A = [&](int c, u64 (&ar)[2][2]) {
    const half_t* base; int str; bool sys;
    if (mode0) {
      if (c == 0) { base = s0; str = str0; sys = sysA0; }
      else        { base = sA + (size_t)(c - 1) * 64; str = H_; sys = true; }
    } else {
      base = (c < 8) ? sA + (size_t)c * 64 : sB + (size_t)(c - 8) * 64;
      str = H_; sys = true;
    }
#pragma unroll
    for (int ii = 0; ii < 2; ++ii) {
      int i = 2 * w + ii;
      int r = 8 * i + r8;
      int sc = c8 ^ r8;
      const half_t* p = base + (size_t)r * str + sc * 8;
      if (sys) {
        ar[ii][0] = sys_ld8(p);
        ar[ii][1] = sys_ld8(p + 4);
      } else {
        ar[ii][0] = ((const u64*)p)[0];
        ar[ii][1] = ((const u64*)p)[1];
      }
    }
  };
  auto write_A = [&](int buf, u64 (&ar)[2][2]) {
    half_t* la = ldsA + buf * 4096;
#pragma unroll
    for (int ii = 0; ii < 2; ++ii) {
      int i = 2 * w + ii;
      u64x2 v = {ar[ii][0], ar[ii][1]};
      *(u64x2*)(la + i * 512 + 64 * r8 + 8 * c8) = v;   // one ds_write_b128
    }
  };
  auto stage_B = [&](int c, int buf) {
    half_t* lb = ldsB + buf * 8192;
    const half_t* bsrc = Bs + (size_t)c * 64;
#pragma unroll
    for (int jj = 0; jj < 4; ++jj) {
      int j = 4 * w + jj;
      int r = 8 * j + r8;
      int sc = c8 ^ r8;
      async_cp16(bsrc + (size_t)r * K + sc * 8, lb + j * 512);
    }
  };

  u64 ar[2][2][2];
  issue_A(0, ar[0]);
  write_A(0, ar[0]);     // compiler inserts the vmcnt wait (tracked loads)
  stage_B(0, 0);
  issue_A(1, ar[1]);
  int buf = 0;
  for (int c = 0; c < NC; ++c) {
    __syncthreads();     // vmcnt(0) drain: buf B staged, prefetched A in regs
    if (c + 2 < NC) issue_A(c + 2, ar[c & 1]);   // ar[c&1] free (chunk c in LDS)
    if (c + 1 < NC) {
      write_A(buf ^ 1, ar[(c + 1) & 1]);
      stage_B(c + 1, buf ^ 1);
    }
    const half_t* la = ldsA + buf * 4096;
    const half_t* lb = ldsB + buf * 8192;
#pragma unroll
    for (int kk = 0; kk < 2; ++kk) {
      half8 av[2], bv[4];
#pragma unroll
      for (int mt = 0; mt < 2; ++mt) {
        int r = wm * 32 + mt * 16 + fr;
        int sc = (4 * kk + q) ^ (fr & 7);
        av[mt] = *(const half8*)(la + r * 64 + sc * 8);
      }
#pragma unroll
      for (int nt = 0; nt < 4; ++nt) {
        int r = wn * 64 + nt * 16 + fr;
        int sc = (4 * kk + q) ^ (fr & 7);
        bv[nt] = *(const half8*)(lb + r * 64 + sc * 8);
      }
#pragma unroll
      for (int mt = 0; mt < 2; ++mt)
#pragma unroll
        for (int nt = 0; nt < 4; ++nt)
          acc[mt][nt] = __builtin_amdgcn_mfma_f32_16x16x32_f16(av[mt], bv[nt], acc[mt][nt], 0, 0, 0);
    }
    buf ^= 1;
  }

  // epilogue: bias + (i,f,g,o) shfl-gather + register-resident cell update;
  // h via dedicated ldsH, then wide system-scope stores.
  const int base = l & ~3;
  const int gsel = l & 3;
#pragma unroll
  for (int nt = 0; nt < 4; ++nt) {
    const int ncl = wn * 64 + nt * 16 + fr;   // local gate col
    const float bc = bp[N0 + ncl];
    const int lc = ncl >> 2;                  // local cell col 0..31
#pragma unroll
    for (int mt = 0; mt < 2; ++mt) {
      const float csnap = creg[nt * 2 + mt];  // pre-update snapshot
#pragma unroll
      for (int r = 0; r < 4; ++r) {
        float v = acc[mt][nt][r] + bc;
        float gi = __shfl(v, base + 0);
        float gf = __shfl(v, base + 1);
        float gg = __shfl(v, base + 2);
        float go = __shfl(v, base + 3);
        float cold = __shfl(csnap, base + r); // keeper lane gsel==r
        const float cn = fast_sig(gf) * cold + fast_sig(gi) * fast_tanh(gg);
        const float hn = fast_sig(go) * fast_tanh(cn);
        if (gsel == r) creg[nt * 2 + mt] = cn;
        if (gsel == 0) {
          const int lm = wm * 32 + mt * 16 + q * 4 + r;
          ldsH[lm * 32 + lc] = (half_t)hn;
        }
      }
    }
  }
  __syncthreads();
  {
    const int tr = tid >> 2, cg = tid & 3;
    const u64* lp = (const u64*)(ldsH + tr * 32 + cg * 8);
    half_t* dst = hout + (size_t)(M0 + tr) * H_ + (N0 >> 2) + cg * 8;
    sys_st8(dst, lp[0]);
    sys_st8(dst + 4, lp[1]);
  }
}

// ---------------- the persistent kernel ----------------

__global__ __launch_bounds__(256, 1)
void k_seq(const half_t* __restrict__ xf,
           const half_t* __restrict__ Wp0e, const float* __restrict__ bp0e,
           const half_t* __restrict__ Wp1e, const float* __restrict__ bp1e,
           const half_t* __restrict__ Wp0d, const float* __restrict__ bp0d,
           const half_t* __restrict__ Wp1d, const float* __restrict__ bp1d,
           half_t* __restrict__ h0, half_t* __restrict__ h1,
           half_t* __restrict__ dpad,
           const float* __restrict__ Wfc, const float* __restrict__ bfc,
           float* __restrict__ out,
           int* __restrict__ fh0, int* __restrict__ fh1, int* __restrict__ ffc) {
  __shared__ __align__(16) half_t ldsA[2 * 64 * 64];    // 16 KB
  __shared__ __align__(16) half_t ldsB[2 * 128 * 64];   // 32 KB
  __shared__ __align__(16) half_t ldsH[64 * 32];        // 4 KB (dedicated)

  const int tid = threadIdx.x;
  const int bid = blockIdx.x;
  // same-n clustering per XCD: weight slab (~1.6MB/XCD) stays L2-resident
  const int n = 2 * (bid & 7) + ((bid >> 3) & 1);
  const int m = bid >> 4;
  const int M0 = m * 64, N0 = n * 128;

  half_t* h0s[3] = {h0, h0 + BH_, h0 + 2 * BH_};
  half_t* h1s[3] = {h1, h1 + BH_, h1 + 2 * BH_};

  float c0r[8], c1r[8];
#pragma unroll
  for (int i = 0; i < 8; ++i) { c0r[i] = 0.0f; c1r[i] = 0.0f; }

  // -------- encoder: phase u does L0e(u) || L1e(u-1) --------
  for (int u = 0; u <= S_; ++u) {
    if (tid == 0) {
      if (u >= 1) wait_ge(fh0 + (u + 1) * 16 + m, 16);   // h0(u-1)
      if (u >= 2) wait_ge(fh1 + u * 16 + m, 16);         // h1(u-2)
    }
    __syncthreads();
    const int sp = (u + 2) % 3, scur = u % 3, spp = (u + 1) % 3;
    if (u < S_) {
      gemm_cell(ldsA, ldsB, ldsH, true, false,
                xf + ((size_t)u * B_ + M0) * 64, 64,
                h0s[sp] + (size_t)M0 * H_, (const half_t*)0,
                Wp0e + (size_t)N0 * 576, 576, 9,
                bp0e, c0r, h0s[scur], M0, N0);
      __syncthreads();                                   // drains sys stores
      if (tid == 0) bump(fh0 + (u + 2) * 16 + m);
    }
    if (u >= 1) {
      gemm_cell(ldsA, ldsB, ldsH, false, false, (const half_t*)0, 0,
                h0s[sp] + (size_t)M0 * H_, h1s[spp] + (size_t)M0 * H_,
                Wp1e + (size_t)N0 * 1024, 1024, 16,
                bp1e, c1r, h1s[sp], M0, N0);
      __syncthreads();
      if (tid == 0) bump(fh1 + (u + 1) * 16 + m);
    }
  }

  // -------- decoder --------
  for (int t = 0; t < HOR_; ++t) {
    const int u = S_ + t;
    if (tid == 0) {
      wait_ge(fh0 + (u + 1) * 16 + m, 16);               // h0(u-1)
      wait_ge(fh1 + (u + 1) * 16 + m, 16);               // h1(u-1)
      if (t >= 1) wait_ge(ffc + (t - 1) * 16 + m, 1);    // dpad(t)
    }
    __syncthreads();
    const int sp = (u + 2) % 3, scur = u % 3;
    gemm_cell(ldsA, ldsB, ldsH, true, true,
              dpad + (size_t)M0 * 64, 64,
              h0s[sp] + (size_t)M0 * H_, (const half_t*)0,
              Wp0d + (size_t)N0 * 576, 576, 9,
              bp0d, c0r, h0s[scur], M0, N0);
    __syncthreads();
    if (tid == 0) {
      bump(fh0 + (u + 2) * 16 + m);
      wait_ge(fh0 + (u + 2) * 16 + m, 16);               // all of h0(t)
    }
    __syncthreads();
    gemm_cell(ldsA, ldsB, ldsH, false, false, (const half_t*)0, 0,
              h0s[scur] + (size_t)M0 * H_, h1s[sp] + (size_t)M0 * H_,
              Wp1d + (size_t)N0 * 1024, 1024, 16,
              bp1d, c1r, h1s[scur], M0, N0);
    __syncthreads();
    if (tid == 0) bump(fh1 + (u + 2) * 16 + m);
    if (n == 0) {                                        // WG (m,0): FC + feedback
      if (tid == 0) wait_ge(fh1 + (u + 2) * 16 + m, 16);
      __syncthreads();
      for (int half = 0; half < 2; ++half) {
        // stage 32 h1 rows (32 KB) into ldsB via system loads
#pragma unroll
        for (int i = 0; i < 16; ++i) {
          int li = tid * 16 + i;                 // 0..4095
          int rr = li >> 7, ee = li & 127;       // row 0..31, 8B-chunk 0..127
          ((u64*)ldsB)[li] =
              sys_ld8(h1s[scur] + (size_t)(M0 + half * 32 + rr) * H_ + ee * 4);
        }
        __syncthreads();
        const int r = tid >> 3, cc = tid & 7;
        const int rowg = M0 + half * 32 + r;
        const half_t* hl = ldsB + r * 512;
        const float* wr = Wfc + cc * H_;
        float s = bfc[cc];
#pragma unroll 8
        for (int k8 = 0; k8 < H_ / 8; ++k8) {
          half8 hv = *(const half8*)(hl + k8 * 8);
#pragma unroll
          for (int e = 0; e < 8; ++e) s += (float)hv[e] * wr[k8 * 8 + e];
        }
        out[((size_t)rowg * HOR_ + t) * NT_ + cc] = s;
        float sn = __shfl(s, (tid & 63) + 1);            // pair-neighbor
        if (!(cc & 1)) {
          unsigned pk = (unsigned)__builtin_bit_cast(unsigned short, (half_t)s)
                      | ((unsigned)__builtin_bit_cast(unsigned short, (half_t)sn) << 16);
          sys_st4(dpad + rowg * 64 + cc, pk);
        }
        __syncthreads();
      }
      if (tid == 0) bump(ffc + t * 16 + m);
    }
  }
}

// ---------------- host ----------------

extern "C" void kernel_launch(void* const* d_in, const int* in_sizes, int n_in,
                              void* d_out, int out_size, void* d_ws, size_t ws_size,
                              hipStream_t stream) {
  (void)in_sizes; (void)n_in; (void)out_size; (void)ws_size;
  const float* x     = (const float*)d_in[0];
  const float* Wih0e = (const float*)d_in[1];
  const float* Whh0e = (const float*)d_in[2];
  const float* b0e   = (const float*)d_in[3];
  const float* Wih1e = (const float*)d_in[4];
  const float* Whh1e = (const float*)d_in[5];
  const float* b1e   = (const float*)d_in[6];
  const float* Wih0d = (const float*)d_in[7];
  const float* Whh0d = (const float*)d_in[8];
  const float* b0d   = (const float*)d_in[9];
  const float* Wih1d = (const float*)d_in[10];
  const float* Whh1d = (const float*)d_in[11];
  const float* b1d   = (const float*)d_in[12];
  const float* Wfc   = (const float*)d_in[13];
  const float* bfc   = (const float*)d_in[14];
  float* out = (float*)d_out;

  char* p = (char*)d_ws;
  auto alloc = [&](size_t bytes) {
    char* r = p;
    p += (bytes + 255) & ~(size_t)255;
    return r;
  };
  half_t* xf   = (half_t*)alloc((size_t)S_ * B_ * 64 * 2);
  half_t* Wp0e = (half_t*)alloc((size_t)NG_ * 576 * 2);
  half_t* Wp1e = (half_t*)alloc((size_t)NG_ * 1024 * 2);
  half_t* Wp0d = (half_t*)alloc((size_t)NG_ * 576 * 2);
  half_t* Wp1d = (half_t*)alloc((size_t)NG_ * 1024 * 2);
  float*  bp0e = (float*)alloc(NG_ * 4);
  float*  bp1e = (float*)alloc(NG_ * 4);
  float*  bp0d = (float*)alloc(NG_ * 4);
  float*  bp1d = (float*)alloc(NG_ * 4);
  half_t* h0   = (half_t*)alloc((size_t)3 * BH_ * 2);
  half_t* h1   = (half_t*)alloc((size_t)3 * BH_ * 2);
  half_t* dpad = (half_t*)alloc((size_t)B_ * 64 * 2);
  int*    fh0  = (int*)alloc(384 * 16 * 4);
  int*    fh1  = (int*)alloc(384 * 16 * 4);
  int*    ffc  = (int*)alloc(32 * 16 * 4);

  k_xT<<<(S_ * B_ * 64) / 256, 256, 0, stream>>>(x, xf);
  k_pack<<<(NG_ * 576) / 256, 256, 0, stream>>>(Wih0e, Whh0e, b0e, Wp0e, bp0e, 64, 64, 576);
  k_pack<<<(NG_ * 1024) / 256, 256, 0, stream>>>(Wih1e, Whh1e, b1e, Wp1e, bp1e, 512, 512, 1024);
  k_pack<<<(NG_ * 576) / 256, 256, 0, stream>>>(Wih0d, Whh0d, b0d, Wp0d, bp0d, 8, 64, 576);
  k_pack<<<(NG_ * 1024) / 256, 256, 0, stream>>>(Wih1d, Whh1d, b1d, Wp1d, bp1d, 512, 512, 1024);
  k_init<<<BH_ / 256, 256, 0, stream>>>(h0, h1, dpad, fh0, fh1, ffc);

  k_seq<<<256, 256, 0, stream>>>(xf, Wp0e, bp0e, Wp1e, bp1e, Wp0d, bp0d, Wp1d, bp1d,
                                 h0, h1, dpad, Wfc, bfc, out, fh0, fh1, ffc);
}